// Round 1
// 202.959 us; speedup vs baseline: 1.0505x; 1.0505x over previous
//
#include <hip/hip_runtime.h>
#include <hip/hip_bf16.h>

#define L_ 256
#define H_ 4
#define ROWS 2048
#define NEGV (-4294967295.0f)   // -(2^32)+1 as float

typedef unsigned short us16;

__device__ __forceinline__ float us2f(us16 u){ return __uint_as_float(((unsigned)u)<<16); }
__device__ __forceinline__ us16 f2us(float f){ __hip_bfloat16 h=__float2bfloat16(f); return *(us16*)&h; }

// dual bf16 MAC: c += lo(x)*lo(y) + hi(x)*hi(y)  (v_dot2_f32_bf16 when available)
__device__ __forceinline__ float dot2bf(unsigned x, unsigned y, float c){
#if __has_builtin(__builtin_amdgcn_fdot2_f32_bf16)
    typedef __bf16 bf2 __attribute__((ext_vector_type(2)));
    union U{ unsigned u; bf2 v; };
    U ux, uy; ux.u=x; uy.u=y;
    return __builtin_amdgcn_fdot2_f32_bf16(ux.v, uy.v, c, false);
#else
    float r=fmaf(us2f((us16)(x&0xffffu)), us2f((us16)(y&0xffffu)), c);
    return fmaf(us2f((us16)(x>>16)), us2f((us16)(y>>16)), r);
#endif
}

struct KArgs {
    const int *log_seqs, *tmat, *pos_seqs, *neg_seqs;
    const float *item_emb, *posK, *posV, *timeK, *timeV;
    const float *ln1g, *ln1b, *bq, *bk, *bv, *ln2g, *ln2b, *b1, *b2, *lnfg, *lnfb;
    const float *Wq, *Wk, *Wv, *W1, *W2;
    float *qin0, *qin1, *out;
    unsigned *wsP;              // 7 x 8192 u32, pair-major bf16 weights: u32[kp*128+c] = {W[2kp][c], W[2kp+1][c]}
    us16 *tmK, *tmV, *Qb0, *Kb0, *Vb0, *Qb1, *Kb1, *Vb1;   // Vb* are k-pair-major u32-packed
};

// LayerNorm of 8 LDS rows in place; thread t: row t>>5, 4 elems strided 32.
__device__ __forceinline__ void ln_rows(float* sA,
        const float* __restrict__ g, const float* __restrict__ b,
        float* qin_out, int r0, int tid){
    int r=tid>>5, l=tid&31;
    float* x=sA+r*128;
    float x0=x[l],x1=x[l+32],x2=x[l+64],x3=x[l+96];
    float s=x0+x1+x2+x3;
    #pragma unroll
    for(int o=16;o;o>>=1) s+=__shfl_xor(s,o,64);
    float m=s*(1.f/128.f);
    float d0=x0-m,d1=x1-m,d2=x2-m,d3=x3-m;
    float v=d0*d0+d1*d1+d2*d2+d3*d3;
    #pragma unroll
    for(int o=16;o;o>>=1) v+=__shfl_xor(v,o,64);
    float rstd=rsqrtf(v*(1.f/128.f)+1e-8f);
    float y0=d0*rstd*g[l]+b[l];
    float y1=d1*rstd*g[l+32]+b[l+32];
    float y2=d2*rstd*g[l+64]+b[l+64];
    float y3=d3*rstd*g[l+96]+b[l+96];
    x[l]=y0; x[l+32]=y1; x[l+64]=y2; x[l+96]=y3;
    if(qin_out){
        float* q=qin_out+(size_t)(r0+r)*128;
        q[l]=y0; q[l+32]=y1; q[l+64]=y2; q[l+96]=y3;
    }
}

// 128-deep GEMV column: out_c = sum_k x[k]*W[k][c]; x packed bf16 pairs in LDS (64 u32),
// W pair-major in global (u32[kp*128+c]). 2 accumulation chains for ILP.
__device__ __forceinline__ float gemv128(const unsigned* __restrict__ wp,
                                         const unsigned* __restrict__ xp, int c){
    float s0=0.f, s1=0.f;
    #pragma unroll 8
    for(int kp=0;kp<64;kp+=2){
        s0=dot2bf(xp[kp],   wp[kp*128+c],     s0);
        s1=dot2bf(xp[kp+1], wp[(kp+1)*128+c], s1);
    }
    return s0+s1;
}

// k_pre: bid<768: embed+LN1+QKV(L0) with f32 weights streamed from global (no LDS staging).
//        bid 768..879: convert 7 weight mats fp32 -> pair-major bf16 u32 into wsP.
//        bid 880..945: convert timeK/timeV tables to bf16 (natural d-pair layout).
__global__ __launch_bounds__(256) void k_pre(KArgs a){
    __shared__ __align__(16) float sA[1024];
    int tid=threadIdx.x, bid=blockIdx.x;
    if(bid<768){
        int m=bid>>8, rg=bid&255, r0=rg*8;
        {   // embed 8 rows: thread -> (row tid>>5, float4 chunk tid&31)
            int rl=tid>>5, c4=tid&31;
            int id=a.log_seqs[r0+rl];
            float4 v=((const float4*)a.item_emb)[id*32+c4];
            float sc = id? 11.3137085f : 0.f;   // sqrt(128), pad-zeroed
            v.x*=sc; v.y*=sc; v.z*=sc; v.w*=sc;
            ((float4*)sA)[tid]=v;
        }
        __syncthreads();
        if(m==0){ ln_rows(sA, a.ln1g, a.ln1b, a.qin0, r0, tid); __syncthreads(); }
        const float* Wsrc=(m==0)?a.Wq:(m==1)?a.Wk:a.Wv;
        int cp=tid&63, rp=tid>>6, c0=2*cp, ra=2*rp, rb=ra+1;
        float a00=0,a01=0,a10=0,a11=0;
        const float* Ar=sA+ra*128;
        const float* Br=sA+rb*128;
        #pragma unroll 8
        for(int kk=0;kk<128;kk++){
            float2 wp=((const float2*)(Wsrc+(size_t)kk*128))[cp];  // coalesced 512B/wave, L2-hit
            float x0=Ar[kk], x1=Br[kk];
            a00=fmaf(x0,wp.x,a00); a01=fmaf(x0,wp.y,a01);
            a10=fmaf(x1,wp.x,a10); a11=fmaf(x1,wp.y,a11);
        }
        int r_a=r0+ra, r_b=r0+rb;                 // r_a even, r_b=r_a+1
        if(m==0){
            float b0v=a.bq[c0], b1v=a.bq[c0+1];
            ushort2 s0; s0.x=f2us(a00+b0v); s0.y=f2us(a01+b1v);
            ushort2 s1; s1.x=f2us(a10+b0v); s1.y=f2us(a11+b1v);
            *(ushort2*)(a.Qb0+(size_t)r_a*128+c0)=s0;
            *(ushort2*)(a.Qb0+(size_t)r_b*128+c0)=s1;
        } else if(m==1){
            float b0v=a.bk[c0], b1v=a.bk[c0+1];
            int qa=r_a&255, qb2=r_b&255;
            ushort2 s0; s0.x=f2us(a00+b0v+a.posK[qa*128+c0]);  s0.y=f2us(a01+b1v+a.posK[qa*128+c0+1]);
            ushort2 s1; s1.x=f2us(a10+b0v+a.posK[qb2*128+c0]); s1.y=f2us(a11+b1v+a.posK[qb2*128+c0+1]);
            *(ushort2*)(a.Kb0+(size_t)r_a*128+c0)=s0;
            *(ushort2*)(a.Kb0+(size_t)r_b*128+c0)=s1;
        } else {
            // V: k-pair-major u32 store: u32[(r/2)*128+c] = {row r_a, row r_b}
            float b0v=a.bv[c0], b1v=a.bv[c0+1];
            int qa=r_a&255, qb2=r_b&255;
            unsigned lo0=f2us(a00+b0v+a.posV[qa*128+c0]);
            unsigned lo1=f2us(a01+b1v+a.posV[qa*128+c0+1]);
            unsigned hi0=f2us(a10+b0v+a.posV[qb2*128+c0]);
            unsigned hi1=f2us(a11+b1v+a.posV[qb2*128+c0+1]);
            unsigned* Vo=(unsigned*)a.Vb0+((size_t)r_a>>1)*128;
            Vo[c0]  =lo0|(hi0<<16);
            Vo[c0+1]=lo1|(hi1<<16);
        }
    } else if(bid<880){
        int j=bid-768; int m=j>>4; int sub=j&15;
        const float* base;
        switch(m){
            case 0: base=a.W1; break;        case 1: base=a.W2; break;
            case 2: base=a.Wq+16384; break;  case 3: base=a.Wk+16384; break;
            case 4: base=a.Wv+16384; break;  case 5: base=a.W1+16384; break;
            default: base=a.W2+16384; break;
        }
        unsigned* dst=a.wsP+(size_t)m*8192;
        #pragma unroll
        for(int t2=0;t2<2;t2++){
            int o=sub*512+t2*256+tid;
            int kp=o>>7, c=o&127;
            unsigned lo=f2us(base[(size_t)(2*kp)*128+c]);
            unsigned hi=f2us(base[(size_t)(2*kp+1)*128+c]);
            dst[o]=lo|(hi<<16);
        }
    } else {
        int gi=(bid-880)*256+tid;     // 2 x 8224 float4
        if(gi<8224){
            float4 v=((const float4*)a.timeK)[gi];
            ushort4 o; o.x=f2us(v.x);o.y=f2us(v.y);o.z=f2us(v.z);o.w=f2us(v.w);
            ((ushort4*)a.tmK)[gi]=o;
        } else if(gi<16448){
            int g2=gi-8224;
            float4 v=((const float4*)a.timeV)[g2];
            ushort4 o; o.x=f2us(v.x);o.y=f2us(v.y);o.z=f2us(v.z);o.w=f2us(v.w);
            ((ushort4*)a.tmV)[g2]=o;
        }
    }
}

// k_blk: one block per (b, q-pair {p,255-p}).
// attention -> LN2 -> FFN -> mask, then (layer0) LN1+QKV of layer1, (layer1) LNf+logits.
// All bf16 MAC work via v_dot2_f32_bf16; weights streamed from L2 (no LDS staging).
__global__ __launch_bounds__(256,4) void k_blk(KArgs a, int layer){
    __shared__ __align__(16) float    sS[8*256];     // 8KB raw scores (f32, scaled)
    __shared__ __align__(16) unsigned sAb[8*128];    // 4KB softmax out, bf16 pairs along k
    __shared__ __align__(16) unsigned sQb[128];      // 512B raw Q bf16 pairs (2 rows)
    __shared__ __align__(16) int      sTM[512];      // 2KB
    __shared__ __align__(16) float    sPr[16*128];   // 8KB AV partials
    __shared__ float sRed[4], sRed2[4], sRB[8];
    __shared__ __align__(16) float    sX[256];       // f32 LN2 out / LNf scratch
    __shared__ __align__(16) unsigned sXb[128];      // bf16-pair LN2 out (GEMV input)
    __shared__ __align__(16) unsigned sHb[128];      // bf16-pair relu h
    __shared__ __align__(16) unsigned sYb[128];      // bf16-pair f (L0 K/V gemv input)

    int tid=threadIdx.x, bid=blockIdx.x;
    int b=bid>>7, p=bid&127;
    int q1=p, q2=255-p, b0=b*L_;
    int r1=b0+q1, r2=b0+q2;
    bool pad1=a.log_seqs[r1]==0, pad2=a.log_seqs[r2]==0;
    const us16* Qb = layer? a.Qb1:a.Qb0;
    const us16* Kb = layer? a.Kb1:a.Kb0;
    const unsigned* Vbu = (const unsigned*)(layer? a.Vb1:a.Vb0);  // pair-major
    const float* qin = layer? a.qin1:a.qin0;
    const float scale=0.17677669529663687f;   // 1/sqrt(32)

    if(tid<128){
        int rowq=tid>>6, j=tid&63;
        int r=rowq?r2:r1;
        sQb[rowq*64+j]=((const unsigned*)Qb)[(size_t)r*64+j];   // raw bf16 pairs, unscaled
    }
    int k=tid;
    int tm1=a.tmat[(size_t)r1*L_+k], tm2=a.tmat[(size_t)r2*L_+k];
    sTM[k]=tm1; sTM[256+k]=tm2;
    __syncthreads();

    // phase 1: scores = (Q . (K' + timeK[tm])) * scale ; dot2 over dim pairs
    {
        const uint4* K4=(const uint4*)(Kb+(size_t)(b0+k)*128);
        #pragma unroll
        for(int i2=0;i2<2;i2++){
            int qq=i2?q2:q1; bool pad=i2?pad2:pad1;
            int tm=i2?tm2:tm1;
            bool act=(k<=qq)&&!pad;
            float acc[4]={0.f,0.f,0.f,0.f};
            if(act){
                const uint4* T4=(const uint4*)(a.tmK+(size_t)tm*128);
                const uint4* Q4=(const uint4*)(sQb+i2*64);
                #pragma unroll
                for(int c=0;c<16;c++){
                    uint4 kv=K4[c], tv=T4[c], qv=Q4[c];
                    float t=acc[c>>2];
                    t=dot2bf(qv.x,kv.x,t); t=dot2bf(qv.y,kv.y,t);
                    t=dot2bf(qv.z,kv.z,t); t=dot2bf(qv.w,kv.w,t);
                    t=dot2bf(qv.x,tv.x,t); t=dot2bf(qv.y,tv.y,t);
                    t=dot2bf(qv.z,tv.z,t); t=dot2bf(qv.w,tv.w,t);
                    acc[c>>2]=t;
                }
            }
            #pragma unroll
            for(int h2=0;h2<H_;h2++) sS[(i2*4+h2)*256+k]= act? acc[h2]*scale : NEGV;
        }
    }
    __syncthreads();

    // phase 2: softmax; wave h -> head h, both queries; emit bf16 A to sAb
    {
        int h=tid>>6, lane=tid&63;
        us16* sab=(us16*)sAb;
        #pragma unroll
        for(int i2=0;i2<2;i2++){
            const float* row=sS+(i2*4+h)*256;
            float v0=row[lane],v1=row[lane+64],v2=row[lane+128],v3=row[lane+192];
            float mm=fmaxf(fmaxf(v0,v1),fmaxf(v2,v3));
            #pragma unroll
            for(int o=32;o;o>>=1) mm=fmaxf(mm,__shfl_xor(mm,o,64));
            float e0=__expf(v0-mm),e1=__expf(v1-mm),e2=__expf(v2-mm),e3=__expf(v3-mm);
            float ss=e0+e1+e2+e3;
            #pragma unroll
            for(int o=32;o;o>>=1) ss+=__shfl_xor(ss,o,64);
            float inv=1.f/ss;
            us16* ar=sab+(i2*4+h)*256;
            ar[lane]    =f2us(e0*inv); ar[lane+64] =f2us(e1*inv);
            ar[lane+128]=f2us(e2*inv); ar[lane+192]=f2us(e3*inv);
        }
    }
    __syncthreads();

    // phase 3: A @ (V'+timeV[tm]); k-pairs: V pair-major direct, timeV packed via v_perm
    {
        int i2=tid>>7, s8=(tid>>4)&7, dq=tid&15;    // 8 dims/thread, head=dq>>2
        int qq=i2?q2:q1; bool pad=i2?pad2:pad1;
        int kend=pad?L_:qq+1;
        int k0=s8*32;
        int kmax=kend-k0; kmax=kmax<0?0:(kmax>32?32:kmax);
        int npair=(kmax+1)>>1;                      // odd tail safe: A==0 beyond kend
        const unsigned* arow=sAb+(i2*4+(dq>>2))*128;
        const int* tmrow=sTM+i2*256;
        float ac0=0,ac1=0,ac2=0,ac3=0,ac4=0,ac5=0,ac6=0,ac7=0;
        for(int kp=0;kp<npair;kp++){
            int kx=k0+2*kp;
            unsigned aa=arow[kx>>1];                // (A[kx], A[kx+1]) bf16 pair
            int tma=tmrow[kx], tmb=tmrow[kx+1];
            const uint4* Vp=(const uint4*)(Vbu+((size_t)(b0+kx)>>1)*128+dq*8);
            uint4 va=Vp[0], vb4=Vp[1];
            uint4 ta=((const uint4*)(a.tmV+(size_t)tma*128))[dq];
            uint4 tb=((const uint4*)(a.tmV+(size_t)tmb*128))[dq];
            ac0=dot2bf(aa,va.x,ac0);  ac1=dot2bf(aa,va.y,ac1);
            ac2=dot2bf(aa,va.z,ac2);  ac3=dot2bf(aa,va.w,ac3);
            ac4=dot2bf(aa,vb4.x,ac4); ac5=dot2bf(aa,vb4.y,ac5);
            ac6=dot2bf(aa,vb4.z,ac6); ac7=dot2bf(aa,vb4.w,ac7);
            unsigned p0=__builtin_amdgcn_perm(tb.x,ta.x,0x05040100u);  // (ta.lo, tb.lo)
            unsigned p1=__builtin_amdgcn_perm(tb.x,ta.x,0x07060302u);  // (ta.hi, tb.hi)
            unsigned p2=__builtin_amdgcn_perm(tb.y,ta.y,0x05040100u);
            unsigned p3=__builtin_amdgcn_perm(tb.y,ta.y,0x07060302u);
            unsigned p4=__builtin_amdgcn_perm(tb.z,ta.z,0x05040100u);
            unsigned p5=__builtin_amdgcn_perm(tb.z,ta.z,0x07060302u);
            unsigned p6=__builtin_amdgcn_perm(tb.w,ta.w,0x05040100u);
            unsigned p7=__builtin_amdgcn_perm(tb.w,ta.w,0x07060302u);
            ac0=dot2bf(aa,p0,ac0); ac1=dot2bf(aa,p1,ac1);
            ac2=dot2bf(aa,p2,ac2); ac3=dot2bf(aa,p3,ac3);
            ac4=dot2bf(aa,p4,ac4); ac5=dot2bf(aa,p5,ac5);
            ac6=dot2bf(aa,p6,ac6); ac7=dot2bf(aa,p7,ac7);
        }
        float* dst=sPr+(i2*8+s8)*128+dq*8;
        ((float4*)dst)[0]=make_float4(ac0,ac1,ac2,ac3);
        ((float4*)dst)[1]=make_float4(ac4,ac5,ac6,ac7);
    }
    __syncthreads();

    // epilogue: +qin residual, LN2 -> sX (f32) + sXb (bf16 pairs)
    int ii=tid>>7, l=tid&127;
    bool padown = ii? pad2:pad1;
    int rr = ii? r2:r1;
    int qown = ii? q2:q1;
    {
        float v=qin[(size_t)rr*128+l];
        #pragma unroll
        for(int sl=0;sl<8;sl++) v+=sPr[(ii*8+sl)*128+l];
        float s=v;
        #pragma unroll
        for(int o=32;o;o>>=1) s+=__shfl_xor(s,o,64);
        if((tid&63)==0) sRed[ii*2+((tid>>6)&1)]=s;
        __syncthreads();
        float m=(sRed[ii*2]+sRed[ii*2+1])*(1.f/128.f);
        float d=v-m;
        float vv=d*d;
        #pragma unroll
        for(int o=32;o;o>>=1) vv+=__shfl_xor(vv,o,64);
        if((tid&63)==0) sRed2[ii*2+((tid>>6)&1)]=vv;
        __syncthreads();
        float rstd=rsqrtf((sRed2[ii*2]+sRed2[ii*2+1])*(1.f/128.f)+1e-8f);
        float y=d*rstd*a.ln2g[layer*128+l]+a.ln2b[layer*128+l];
        sX[ii*128+l]=y;
        ((us16*)sXb)[ii*128+l]=f2us(y);
    }
    __syncthreads();

    // FFN: h = relu(sX@W1+b1); f = h@W2+b2 + sX; mask. W streamed from L2, dot2 GEMVs.
    int cc=l;
    {
        const unsigned* W1p=a.wsP+(size_t)(layer?5:0)*8192;
        float h1=gemv128(W1p, sXb+ii*64, cc);
        h1=fmaxf(h1+a.b1[layer*128+cc],0.f);
        ((us16*)sHb)[ii*128+cc]=f2us(h1);
    }
    __syncthreads();
    float f;
    {
        const unsigned* W2p=a.wsP+(size_t)(layer?6:1)*8192;
        f=gemv128(W2p, sHb+ii*64, cc)+a.b2[layer*128+cc]+sX[ii*128+cc];
        if(padown) f=0.f;
    }

    if(layer==0){
        // LN1(layer1) on f -> sXb (Q gemv input); raw f -> sYb (K,V gemv input)
        ((us16*)sYb)[ii*128+cc]=f2us(f);
        float s=f;
        #pragma unroll
        for(int o=32;o;o>>=1) s+=__shfl_xor(s,o,64);
        if((tid&63)==0) sRB[ii*2+((tid>>6)&1)]=s;
        __syncthreads();
        float m=(sRB[ii*2]+sRB[ii*2+1])*(1.f/128.f);
        float d=f-m;
        float vv=d*d;
        #pragma unroll
        for(int o=32;o;o>>=1) vv+=__shfl_xor(vv,o,64);
        if((tid&63)==0) sRB[4+ii*2+((tid>>6)&1)]=vv;
        __syncthreads();
        float rstd=rsqrtf((sRB[4+ii*2]+sRB[5+ii*2])*(1.f/128.f)+1e-8f);
        float y1=d*rstd*a.ln1g[128+cc]+a.ln1b[128+cc];
        a.qin1[(size_t)rr*128+cc]=y1;
        ((us16*)sXb)[ii*128+cc]=f2us(y1);
        __syncthreads();
        // Q(L1), K(L1), V(L1): read-only LDS -> no barriers between GEMVs
        float accq=gemv128(a.wsP+(size_t)2*8192, sXb+ii*64, cc)+a.bq[128+cc];
        a.Qb1[(size_t)rr*128+cc]=f2us(accq);
        float acck=gemv128(a.wsP+(size_t)3*8192, sYb+ii*64, cc)+a.bk[128+cc]+a.posK[qown*128+cc];
        a.Kb1[(size_t)rr*128+cc]=f2us(acck);
        float accv=gemv128(a.wsP+(size_t)4*8192, sYb+ii*64, cc)+a.bv[128+cc]+a.posV[qown*128+cc];
        ((us16*)a.Vb1)[((size_t)rr>>1)*256+2*cc+(rr&1)]=f2us(accv);   // pair-major
    } else {
        // LNf + logits
        float s=f;
        #pragma unroll
        for(int o=32;o;o>>=1) s+=__shfl_xor(s,o,64);
        if((tid&63)==0) sRB[ii*2+((tid>>6)&1)]=s;
        __syncthreads();
        float m=(sRB[ii*2]+sRB[ii*2+1])*(1.f/128.f);
        float d=f-m;
        float vv=d*d;
        #pragma unroll
        for(int o=32;o;o>>=1) vv+=__shfl_xor(vv,o,64);
        if((tid&63)==0) sRB[4+ii*2+((tid>>6)&1)]=vv;
        __syncthreads();
        float rstd=rsqrtf((sRB[4+ii*2]+sRB[5+ii*2])*(1.f/128.f)+1e-8f);
        sX[ii*128+cc]=d*rstd*a.lnfg[cc]+a.lnfb[cc];
        __syncthreads();
        int w=tid>>6, lane=tid&63;
        int rowi=w>>1, neg=w&1;
        int rg = rowi? r2:r1;
        int id = neg? a.neg_seqs[rg] : a.pos_seqs[rg];
        const float* e=a.item_emb+(size_t)id*128;
        float s2 = sX[rowi*128+lane]*e[lane] + sX[rowi*128+lane+64]*e[lane+64];
        #pragma unroll
        for(int o=32;o;o>>=1) s2+=__shfl_xor(s2,o,64);
        if(lane==0) a.out[neg*ROWS+rg]=s2;
    }
}

extern "C" void kernel_launch(void* const* d_in, const int* in_sizes, int n_in,
                              void* d_out, int out_size, void* d_ws, size_t ws_size,
                              hipStream_t stream) {
    KArgs a;
    a.log_seqs=(const int*)d_in[1];
    a.tmat    =(const int*)d_in[2];
    a.pos_seqs=(const int*)d_in[3];
    a.neg_seqs=(const int*)d_in[4];
    a.item_emb=(const float*)d_in[5];
    a.posK =(const float*)d_in[6];
    a.posV =(const float*)d_in[7];
    a.timeK=(const float*)d_in[8];
    a.timeV=(const float*)d_in[9];
    a.ln1g=(const float*)d_in[10];
    a.ln1b=(const float*)d_in[11];
    a.Wq=(const float*)d_in[12];
    a.bq=(const float*)d_in[13];
    a.Wk=(const float*)d_in[14];
    a.bk=(const float*)d_in[15];
    a.Wv=(const float*)d_in[16];
    a.bv=(const float*)d_in[17];
    a.ln2g=(const float*)d_in[18];
    a.ln2b=(const float*)d_in[19];
    a.W1=(const float*)d_in[20];
    a.b1=(const float*)d_in[21];
    a.W2=(const float*)d_in[22];
    a.b2=(const float*)d_in[23];
    a.lnfg=(const float*)d_in[24];
    a.lnfb=(const float*)d_in[25];

    const size_t MB=1u<<20;
    char* w=(char*)d_ws;
    a.qin0=(float*)(w+0*MB);
    a.qin1=(float*)(w+1*MB);
    a.Qb0 =(us16*) (w+2*MB);
    a.Kb0 =(us16*) (w+2*MB+512*1024);
    a.Vb0 =(us16*) (w+3*MB);
    a.Qb1 =(us16*) (w+3*MB+512*1024);
    a.Kb1 =(us16*) (w+4*MB);
    a.Vb1 =(us16*) (w+4*MB+512*1024);
    a.wsP =(unsigned*)(w+5*MB);           // 7 x 32KB pair-major bf16
    a.tmK =(us16*) (w+5*MB+256*1024);     // 65792 B
    a.tmV =(us16*) (w+5*MB+384*1024);
    a.out =(float*)d_out;

    k_pre<<<946,256,0,stream>>>(a);
    k_blk<<<1024,256,0,stream>>>(a,0);
    k_blk<<<1024,256,0,stream>>>(a,1);
}